// Round 14
// baseline (165.436 us; speedup 1.0000x reference)
//
#include <hip/hip_runtime.h>

#define BB 16
#define NN 25200
#define NC 80
#define ROWL 85
#define KTOP 4096
#define MAXDET 1000
#define CONF_T 0.55f
#define IOU_T 0.45f
#define MAX_WH_F 7680.0f
#define CAPV 8192      // per-image valid-candidate LDS cap (count ~3450, sd ~55 -> 86 sigma)
#define CCAP 128       // per-class cap (mean ~44, sd ~6.6 -> 12.7 sigma; R4-R12 proved max<=256, likely ~80)
#define NBIN 2048      // rank histogram bins = key bits [54:44]

// ---------------- Kernel 1: per-thread score -> dense per-anchor keys ----------------
// No atomics, no counters, no zeroing: every anchor slot gets key-or-0 each call.
__global__ __launch_bounds__(256) void score_kernel(const float* __restrict__ pred,
                                                    unsigned long long* __restrict__ gkey) {
  const int b = blockIdx.y;
  const int a = blockIdx.x * 256 + threadIdx.x;
  if (a >= NN) return;
  const float* __restrict__ row = pred + ((size_t)b * NN + a) * ROWL;
  unsigned long long key = 0ull;
  float obj = row[4];
  if (obj > CONF_T) {   // conf = cls*obj <= obj, so obj<=T implies invalid
    float b0 = -1.0f, b1 = -1.0f, b2 = -1.0f, b3 = -1.0f;
    int i0 = 0, i1 = 20, i2 = 40, i3 = 60;
    #pragma unroll
    for (int t = 0; t < 20; ++t) {   // 4 independent chains (ILP 4)
      float v0 = row[5 + t] * obj;  if (v0 > b0) { b0 = v0; i0 = t; }       // ref fp order
      float v1 = row[25 + t] * obj; if (v1 > b1) { b1 = v1; i1 = 20 + t; }  // strict > keeps
      float v2 = row[45 + t] * obj; if (v2 > b2) { b2 = v2; i2 = 40 + t; }  // first index
      float v3 = row[65 + t] * obj; if (v3 > b3) { b3 = v3; i3 = 60 + t; }
    }
    float best = b0; int bi = i0;          // merge quarters in order == jnp argmax
    if (b1 > best) { best = b1; bi = i1; }
    if (b2 > best) { best = b2; bi = i2; }
    if (b3 > best) { best = b3; bi = i3; }
    if (best > CONF_T)
      // key: score bits | ~anchor (lower anchor first = lax.top_k tie order) | cls
      key = ((unsigned long long)__float_as_uint(best) << 32) |
            ((unsigned long long)((~(unsigned)a) & 0xFFFFu) << 16) |
            (unsigned long long)(unsigned)bi;
  }
  gkey[(size_t)b * NN + a] = key;
}

// IoU suppress helper (exact reference arithmetic)
__device__ __forceinline__ bool iou_sup(float ax1, float ay1, float ax2, float ay2,
                                        float aar, float bx1, float by1, float bx2,
                                        float by2, float bar) {
  float ltx = fmaxf(ax1, bx1), lty = fmaxf(ay1, by1);
  float rbx = fminf(ax2, bx2), rby = fminf(ay2, by2);
  float wv = rbx - ltx; wv = wv > 0.0f ? wv : 0.0f;
  float hv = rby - lty; hv = hv > 0.0f ? hv : 0.0f;
  float inter = wv * hv;
  float iou = inter / (aar + bar - inter + 1e-7f);
  return iou > IOU_T;
}

// ---------------- Kernel 2: per-image compact + bin + NMS + rank + output ----------------
// One block per image, everything in LDS (~148 KB of the 160 KB/CU; R2 ran 100 KB static).
__global__ __launch_bounds__(1024) void image_kernel(
    const float* __restrict__ pred,
    const unsigned long long* __restrict__ gkey,
    const int* __restrict__ ihp, const int* __restrict__ iwp,
    float* __restrict__ out) {
  __shared__ unsigned long long vkeys[CAPV];       // 64 KiB: valid keys, later kept keys
  __shared__ unsigned long long cbuck[NC * CCAP];  // 80 KiB: class buckets, later hist+skey
  __shared__ unsigned int ccnt[NC];
  __shared__ unsigned int redbuf[16];
  __shared__ unsigned int wsum[16], woff[16];
  __shared__ unsigned int vcnt, kcnt;
  const int b = blockIdx.x;
  const int tid = threadIdx.x;
  const int lane = tid & 63;
  const int w = tid >> 6;
  const float* __restrict__ pb = pred + (size_t)b * NN * ROWL;
  const unsigned long long* __restrict__ gk = gkey + (size_t)b * NN;

  // ---- init ----
  if (tid == 0) { vcnt = 0u; kcnt = 0u; }
  if (tid < NC) ccnt[tid] = 0u;
  __syncthreads();

  // ---- phase B: ballot-compact valid keys into vkeys (order arbitrary) ----
  for (int seg = w; seg < (NN + 63) / 64; seg += 16) {
    int i = seg * 64 + lane;
    unsigned long long k = (i < NN) ? gk[i] : 0ull;
    bool pr = (k != 0ull);
    unsigned long long m = __ballot(pr);
    int nv = (int)__popcll(m);
    unsigned int base = 0;
    if (nv) {
      if (lane == 0) base = atomicAdd(&vcnt, (unsigned int)nv);
      base = (unsigned int)__shfl((int)base, 0, 64);
      if (pr) {
        unsigned int slot = base + (unsigned int)__popcll(m & ((1ull << lane) - 1ull));
        if (slot < (unsigned)CAPV) vkeys[slot] = k;
      }
    }
  }
  __syncthreads();

  const unsigned int count = vcnt;                       // true valid count
  const int nv2 = (int)(count < (unsigned)CAPV ? count : (unsigned)CAPV);

  // ---- phase C: top-KTOP threshold (statistically dead: count ~3450 vs 4096) ----
  if (count > (unsigned)KTOP) {
    unsigned long long T = 0ull;
    for (int bit = 63; bit >= 0; --bit) {
      unsigned long long T2 = T | (1ull << bit);
      unsigned int c = 0;
      for (int i = tid; i < nv2; i += 1024) c += (vkeys[i] >= T2) ? 1u : 0u;
      #pragma unroll
      for (int off = 32; off >= 1; off >>= 1) c += __shfl_down(c, off, 64);
      if (lane == 0) redbuf[w] = c;
      __syncthreads();
      unsigned int total = 0;
      for (int j = 0; j < 16; ++j) total += redbuf[j];   // uniform
      if (total >= (unsigned)KTOP) T = T2;               // keys unique -> exactly KTOP >= T
      __syncthreads();
    }
    for (int i = tid; i < nv2; i += 1024) if (vkeys[i] < T) vkeys[i] = 0ull;
    __syncthreads();
  }

  // ---- phase D: bin into per-class buckets (LDS atomics; order irrelevant) ----
  for (int i = tid; i < nv2; i += 1024) {
    unsigned long long k = vkeys[i];
    if (k) {
      int cls = (int)(k & 0xFFFFu);
      unsigned int slot = atomicAdd(&ccnt[cls], 1u);
      if (slot < (unsigned)CCAP) cbuck[cls * CCAP + slot] = k;
    }
  }
  __syncthreads();

  // ---- phase E: per-class sort + greedy NMS; kept keys -> vkeys[0..kcnt) ----
  // Cross-class IoU exactly 0 (cls*7680 offset) -> per-class greedy == ref global scan.
  #pragma unroll 1
  for (int cc = 0; cc < 5; ++cc) {
    const int c = w + (cc << 4);
    unsigned int pcv = ccnt[c];
    int n_c = (int)(pcv < (unsigned)CCAP ? pcv : (unsigned)CCAP);
    if (n_c == 0) continue;
    const unsigned long long* __restrict__ bkc = &cbuck[c * CCAP];
    const float offc = (float)c * MAX_WH_F;

    if (n_c <= 64) {
      // ======== fast path (proven R7-R12 code, LDS source/sink) ========
      unsigned long long v0 = (lane < n_c) ? bkc[lane] : 0ull;
      for (int k2 = 2; k2 <= 64; k2 <<= 1) {
        for (int j = k2 >> 1; j >= 1; j >>= 1) {
          unsigned long long vo = __shfl_xor(v0, j, 64);
          bool desc = ((lane & k2) == 0);
          bool low = ((lane & j) == 0);
          if ((desc == low) ? (vo > v0) : (vo < v0)) v0 = vo;
        }
      }
      float x1 = 0.f, y1 = 0.f, x2 = 0.f, y2 = 0.f, aar = 0.f;
      const bool inr = (lane < n_c);
      if (inr) {
        unsigned int lo = (unsigned int)v0;
        int aa = (int)((~(lo >> 16)) & 0xFFFFu);
        const float* row = pb + (size_t)aa * ROWL;
        float cx = row[0], cy = row[1], w2 = row[2], h2 = row[3];
        x1 = (cx - w2 / 2.0f) + offc;
        y1 = (cy - h2 / 2.0f) + offc;
        x2 = (cx + w2 / 2.0f) + offc;
        y2 = (cy + h2 / 2.0f) + offc;
        aar = (x2 - x1) * (y2 - y1);
      }
      unsigned long long rowreg = 0ull;
      for (int i2 = 0; i2 < n_c; ++i2) {
        float bx1 = __shfl(x1, i2, 64), by1 = __shfl(y1, i2, 64);
        float bx2 = __shfl(x2, i2, 64), by2 = __shfl(y2, i2, 64);
        float bar = __shfl(aar, i2, 64);
        bool sup = inr && (lane > i2) &&
                   iou_sup(bx1, by1, bx2, by2, bar, x1, y1, x2, y2, aar);
        unsigned long long rm = __ballot(sup);
        if (lane == i2) rowreg = rm;
      }
      unsigned long long cand = (n_c >= 64) ? ~0ull : ((1ull << n_c) - 1ull);
      unsigned long long keepm = 0ull;
      while (cand) {
        int i = __ffsll(cand) - 1;
        keepm |= (1ull << i);
        unsigned long long rowi = __shfl(rowreg, i, 64);
        cand &= ~rowi;
        cand &= ~(1ull << i);
      }
      int keep0 = (int)((keepm >> lane) & 1ull);
      unsigned long long m0 = __ballot(keep0 != 0);
      int tot = (int)__popcll(m0);
      unsigned int base3 = 0;
      if (lane == 0) base3 = atomicAdd(&kcnt, (unsigned int)tot);
      base3 = (unsigned int)__shfl((int)base3, 0, 64);
      if (keep0) {
        unsigned int slot = base3 + (unsigned int)__popcll(m0 & ((1ull << lane) - 1ull));
        if (slot < (unsigned)KTOP) vkeys[slot] = v0;
      }
    } else {
      // ======== slow path (proven R4 4-reg code; n_c <= CCAP=128, regs 2,3 = pads) ====
      unsigned long long v[4];
      #pragma unroll
      for (int r = 0; r < 4; ++r) {
        int e = (r << 6) + lane;
        v[r] = (e < n_c) ? bkc[e] : 0ull;
      }
      for (int k2 = 2; k2 <= 256; k2 <<= 1) {
        if (k2 == 256) {
          #pragma unroll
          for (int r = 0; r < 2; ++r) {
            unsigned e = (unsigned)((r << 6) + lane);
            bool desc = ((e & k2) == 0);
            unsigned long long lo_ = v[r], hi_ = v[r + 2];
            bool sw = desc ? (lo_ < hi_) : (lo_ > hi_);
            v[r] = sw ? hi_ : lo_; v[r + 2] = sw ? lo_ : hi_;
          }
        }
        if (k2 >= 128) {
          #pragma unroll
          for (int rr = 0; rr < 2; ++rr) {
            int r = rr * 2;
            unsigned e = (unsigned)((r << 6) + lane);
            bool desc = ((e & k2) == 0);
            unsigned long long lo_ = v[r], hi_ = v[r + 1];
            bool sw = desc ? (lo_ < hi_) : (lo_ > hi_);
            v[r] = sw ? hi_ : lo_; v[r + 1] = sw ? lo_ : hi_;
          }
        }
        int j0 = (k2 >> 1) < 32 ? (k2 >> 1) : 32;
        for (int j = j0; j >= 1; j >>= 1) {
          #pragma unroll
          for (int r = 0; r < 4; ++r) {
            unsigned e = (unsigned)((r << 6) + lane);
            unsigned long long vo = __shfl_xor(v[r], j, 64);
            bool desc = ((e & k2) == 0);
            bool low = ((e & j) == 0);
            if ((desc == low) ? (vo > v[r]) : (vo < v[r])) v[r] = vo;
          }
        }
      }
      float x1r[4], y1r[4], x2r[4], y2r[4], ar[4];
      int keepr[4];
      #pragma unroll
      for (int r = 0; r < 4; ++r) {
        int e = (r << 6) + lane;
        keepr[r] = 0; x1r[r] = 0.f; y1r[r] = 0.f; x2r[r] = 0.f; y2r[r] = 0.f; ar[r] = 0.f;
        if (e < n_c) {
          unsigned int lo = (unsigned int)v[r];
          int aa = (int)((~(lo >> 16)) & 0xFFFFu);
          const float* row = pb + (size_t)aa * ROWL;
          float cx = row[0], cy = row[1], w2 = row[2], h2 = row[3];
          x1r[r] = (cx - w2 / 2.0f) + offc;
          y1r[r] = (cy - h2 / 2.0f) + offc;
          x2r[r] = (cx + w2 / 2.0f) + offc;
          y2r[r] = (cy + h2 / 2.0f) + offc;
          ar[r] = (x2r[r] - x1r[r]) * (y2r[r] - y1r[r]);
          keepr[r] = 1;
        }
      }
      for (int i2 = 0; i2 < n_c; ++i2) {
        int ci = i2 >> 6, li = i2 & 63;
        int ki; float bx1v, by1v, bx2v, by2v, bav;
        #define BCAST(R) { ki = __shfl(keepr[R], li, 64); bx1v = __shfl(x1r[R], li, 64); \
                           by1v = __shfl(y1r[R], li, 64); bx2v = __shfl(x2r[R], li, 64); \
                           by2v = __shfl(y2r[R], li, 64); bav = __shfl(ar[R], li, 64); }
        switch (ci) {
          case 0: BCAST(0); break;
          case 1: BCAST(1); break;
          case 2: BCAST(2); break;
          default: BCAST(3); break;
        }
        #undef BCAST
        if (!ki) continue;
        #pragma unroll
        for (int r = 0; r < 4; ++r) {
          int e = (r << 6) + lane;
          if (keepr[r] && e > i2 &&
              iou_sup(bx1v, by1v, bx2v, by2v, bav, x1r[r], y1r[r], x2r[r], y2r[r], ar[r]))
            keepr[r] = 0;
        }
      }
      unsigned long long m[4];
      int tot = 0;
      #pragma unroll
      for (int r = 0; r < 4; ++r) {
        m[r] = __ballot(keepr[r] != 0);
        tot += (int)__popcll(m[r]);
      }
      unsigned int base3 = 0;
      if (lane == 0) base3 = atomicAdd(&kcnt, (unsigned int)tot);
      base3 = (unsigned int)__shfl((int)base3, 0, 64);
      unsigned int start = base3;
      #pragma unroll
      for (int r = 0; r < 4; ++r) {
        if (keepr[r]) {
          unsigned int slot = start + (unsigned int)__popcll(m[r] & ((1ull << lane) - 1ull));
          if (slot < (unsigned)KTOP) vkeys[slot] = v[r];
        }
        start += (unsigned int)__popcll(m[r]);
      }
    }
  }
  __syncthreads();

  // ---- phase F: histogram rank + transform + output (proven finalize, LDS source) ----
  // hist/sufx/curs/skey overlay the bucket region (buckets dead after phase E).
  unsigned int* hist = (unsigned int*)cbuck;
  unsigned int* sufx = hist + NBIN;
  unsigned int* curs = hist + 2 * NBIN;
  unsigned long long* skey = (unsigned long long*)(hist + 3 * NBIN);  // 32 KiB, fits
  const int kc = (int)(kcnt < (unsigned)KTOP ? kcnt : (unsigned)KTOP);

  hist[2 * tid] = 0u; hist[2 * tid + 1] = 0u;
  __syncthreads();

  unsigned long long myk[4];
  int myb[4];
  #pragma unroll
  for (int r = 0; r < 4; ++r) {
    int i = tid + (r << 10);
    myb[r] = -1; myk[r] = 0ull;
    if (i < kc) {
      unsigned long long k = vkeys[i];
      int bin = (int)((k >> 44) & (unsigned long long)(NBIN - 1));
      myk[r] = k; myb[r] = bin;
      atomicAdd(&hist[bin], 1u);
    }
  }
  __syncthreads();

  unsigned int h0 = hist[2 * tid], h1 = hist[2 * tid + 1];
  unsigned int v = h0 + h1;
  #pragma unroll
  for (int off = 1; off < 64; off <<= 1) {   // inclusive SUFFIX within wave
    unsigned int o = __shfl_down(v, off, 64);
    if (lane + off < 64) v += o;
  }
  if (lane == 0) wsum[w] = v;
  __syncthreads();
  if (tid < 16) {
    unsigned int s = 0;
    for (int j = tid + 1; j < 16; ++j) s += wsum[j];
    woff[tid] = s;
  }
  __syncthreads();
  unsigned int incl = v + woff[w];
  unsigned int excl = incl - (h0 + h1);
  sufx[2 * tid] = excl + h1;
  sufx[2 * tid + 1] = excl;
  curs[2 * tid] = excl + h1;
  curs[2 * tid + 1] = excl;
  __syncthreads();

  #pragma unroll
  for (int r = 0; r < 4; ++r) {
    if (myb[r] >= 0) {
      unsigned int p = atomicAdd(&curs[myb[r]], 1u);
      skey[p] = myk[r];
    }
  }
  __syncthreads();

  const int h = ihp[0], w3 = iwp[0];
  const double gd = fmin(640.0 / (double)h, 640.0 / (double)w3);
  const float gain = (float)gd;
  const float padx = (float)((640.0 - (double)w3 * gd) * 0.5);
  const float pady = (float)((640.0 - (double)h * gd) * 0.5);
  const float wf = (float)w3, hf = (float)h;
  #pragma unroll
  for (int r = 0; r < 4; ++r) {
    if (myb[r] >= 0) {
      unsigned long long k = myk[r];
      unsigned int gstart = sufx[myb[r]];
      unsigned int gcnt = hist[myb[r]];
      unsigned int rank = gstart;
      for (unsigned int j = 0; j < gcnt; ++j)
        rank += (skey[gstart + j] > k) ? 1u : 0u;   // strict >, excludes self
      if (rank < MAXDET) {
        unsigned int lo = (unsigned int)k;
        int aa = (int)((~(lo >> 16)) & 0xFFFFu);
        int cls = (int)(lo & 0xFFFFu);
        float score = __uint_as_float((unsigned int)(k >> 32));
        const float* row = pb + (size_t)aa * ROWL;
        float cx = row[0], cy = row[1], wd = row[2], ht = row[3];
        float x1 = cx - wd / 2.0f, y1 = cy - ht / 2.0f;
        float x2 = cx + wd / 2.0f, y2 = cy + ht / 2.0f;
        x1 = rintf(fminf(fmaxf((x1 - padx) / gain, 0.0f), wf));
        y1 = rintf(fminf(fmaxf((y1 - pady) / gain, 0.0f), hf));
        x2 = rintf(fminf(fmaxf((x2 - padx) / gain, 0.0f), wf));
        y2 = rintf(fminf(fmaxf((y2 - pady) / gain, 0.0f), hf));
        float* o = out + ((size_t)b * MAXDET + (int)rank) * 6;
        o[0] = x1; o[1] = y1; o[2] = x2; o[3] = y2;
        o[4] = score; o[5] = (float)cls;
      }
    }
  }
  // rows [kc, MAXDET): zero-fill
  for (int i = kc + tid; i < MAXDET; i += 1024) {
    float* o = out + ((size_t)b * MAXDET + i) * 6;
    o[0] = 0.0f; o[1] = 0.0f; o[2] = 0.0f; o[3] = 0.0f; o[4] = 0.0f; o[5] = 0.0f;
  }
}

extern "C" void kernel_launch(void* const* d_in, const int* in_sizes, int n_in,
                              void* d_out, int out_size, void* d_ws, size_t ws_size,
                              hipStream_t stream) {
  const float* pred = (const float*)d_in[0];
  const int* ih = (const int*)d_in[1];
  const int* iw = (const int*)d_in[2];
  float* out = (float*)d_out;
  unsigned long long* gkey = (unsigned long long*)d_ws;   // 16*25200*8 = 3.23 MB

  dim3 sgrid((NN + 255) / 256, BB);
  score_kernel<<<sgrid, 256, 0, stream>>>(pred, gkey);
  image_kernel<<<BB, 1024, 0, stream>>>(pred, gkey, ih, iw, out);
}

// Round 15
// 159.393 us; speedup vs baseline: 1.0379x; 1.0379x over previous
//
#include <hip/hip_runtime.h>

#define BB 16
#define NN 25200
#define NC 80
#define ROWL 85
#define KTOP 4096
#define MAXDET 1000
#define CONF_T 0.55f
#define IOU_T 0.45f
#define MAX_WH_F 7680.0f
#define CNT_STRIDE 32    // per-image counters 128 B apart
#define PCNT_STRIDE 16   // per-(image,class) counters 64 B apart
#define CCAP 256         // per-class candidate cap (mean ~44, sd ~6.6 -> 30+ sigma)
#define NBIN 2048        // rank histogram bins = key bits [54:44]

// ws layout (bytes) — R10 layout (kept pool removed):
//   pcnt   : [0,      81920)   16*80*16 u32  per-(b,c) bucket counters
//   cnt    : [81920,  83968)   16*32 u32     per-image candidate count
//   (pad)  : [83968,  86016)
//   buckets: [86016,  2707456) 16*80*256 u64 per-(b,c) candidate keys
#define OFF_CNT   81920
#define OFF_BUCK  86016
#define ZERO_WORDS 21504   // zeroes [0, 86016)

__global__ void zero_kernel(unsigned int* __restrict__ w) {
  w[blockIdx.x * 256 + threadIdx.x] = 0u;
}

// ---------------- Kernel A: score, 16-lane-group cooperative class scan (R10 verbatim) ----------------
__global__ __launch_bounds__(256) void score_kernel(const float* __restrict__ pred,
                             unsigned long long* __restrict__ buckets,
                             unsigned int* __restrict__ pcnt,
                             unsigned int* __restrict__ cnt) {
  const int b = blockIdx.y;
  const int lane = threadIdx.x & 63;
  const int a0 = blockIdx.x * 256 + (threadIdx.x & ~63);
  const int a = a0 + lane;
  const int g = lane >> 4;     // 16-lane group id [0,4)
  const int gl = lane & 15;    // lane within group
  const float* __restrict__ pb = pred + (size_t)b * NN * ROWL;
  float obj = 0.0f;
  if (a < NN) obj = pb[(size_t)a * ROWL + 4];
  unsigned long long mask = __ballot(obj > CONF_T);
  unsigned int nvacc = 0;
  while (mask) {
    int s0 = __ffsll(mask) - 1; mask &= mask - 1;
    int s1 = -1, s2 = -1, s3 = -1;
    if (mask) { s1 = __ffsll(mask) - 1; mask &= mask - 1; }
    if (mask) { s2 = __ffsll(mask) - 1; mask &= mask - 1; }
    if (mask) { s3 = __ffsll(mask) - 1; mask &= mask - 1; }
    const int sg = (g == 0) ? s0 : (g == 1) ? s1 : (g == 2) ? s2 : s3;
    const bool act = (sg >= 0);
    const int srow = act ? sg : s0;       // inactive groups alias row s0 (broadcast)
    const int aa = a0 + srow;
    const float objg = __shfl(obj, srow, 64);
    const float* __restrict__ row = pb + (size_t)aa * ROWL;
    float best = -1.0f; int bi = gl;
    #pragma unroll
    for (int t = 0; t < 5; ++t) {
      float v = row[5 + gl + 16 * t] * objg;      // exact ref product order
      if (v > best) { best = v; bi = gl + 16 * t; }  // strict > keeps first
    }
    #pragma unroll
    for (int off = 1; off <= 8; off <<= 1) {      // group argmax: value, tie -> min idx
      float ov = __shfl_xor(best, off, 64);
      int oi = __shfl_xor(bi, off, 64);
      if (ov > best || (ov == best && oi < bi)) { best = ov; bi = oi; }
    }
    bool emit = act && (gl == 0) && (best > CONF_T);
    if (emit) {
      // key: score bits | ~anchor (lower anchor first = lax.top_k tie order) | cls
      unsigned long long key =
          ((unsigned long long)__float_as_uint(best) << 32) |
          ((unsigned long long)((~(unsigned)aa) & 0xFFFFu) << 16) |
          (unsigned long long)(unsigned)bi;
      unsigned int slot = atomicAdd(&pcnt[(b * NC + bi) * PCNT_STRIDE], 1u);
      if (slot < CCAP)
        buckets[((size_t)(b * NC + bi) << 8) + slot] = key;
    }
    unsigned long long em = __ballot(emit);
    if (lane == 0) nvacc += (unsigned int)__popcll(em);
  }
  if (lane == 0 && nvacc)
    atomicAdd(&cnt[b * CNT_STRIDE], nvacc);
}

// IoU suppress helper (exact reference arithmetic)
__device__ __forceinline__ bool iou_sup(float ax1, float ay1, float ax2, float ay2,
                                        float aar, float bx1, float by1, float bx2,
                                        float by2, float bar) {
  float ltx = fmaxf(ax1, bx1), lty = fmaxf(ay1, by1);
  float rbx = fminf(ax2, bx2), rby = fminf(ay2, by2);
  float wv = rbx - ltx; wv = wv > 0.0f ? wv : 0.0f;
  float hv = rby - lty; hv = hv > 0.0f ? hv : 0.0f;
  float inter = wv * hv;
  float iou = inter / (aar + bar - inter + 1e-7f);
  return iou > IOU_T;
}

// ---------------- Kernel B: merged NMS + rank + output (16 blocks x 1024) ----------------
// Phase E = R13's proven per-class NMS (16 waves x 5 classes), buckets read from
// GLOBAL (pre-binned by score — R13's fatal compaction phase doesn't exist here),
// with all 5 classes' counters + first-64 keys prefetched up-front so class
// rounds pipeline. Kept keys stay in LDS (no global kept pool, no drain before
// rank). Phase F = R13's proven histogram-rank + transform + output.
__global__ __launch_bounds__(1024) void nms_finalize_kernel(
    const float* __restrict__ pred,
    const unsigned long long* __restrict__ buckets,
    const unsigned int* __restrict__ pcnt,
    const unsigned int* __restrict__ cnt,
    const int* __restrict__ ihp, const int* __restrict__ iwp,
    float* __restrict__ out) {
  __shared__ unsigned long long vkeys[KTOP];   // 32 KiB: kept keys
  __shared__ unsigned int hist[NBIN];          // 8 KiB
  __shared__ unsigned int sufx[NBIN];          // 8 KiB
  __shared__ unsigned int curs[NBIN];          // 8 KiB
  __shared__ unsigned long long skey[KTOP];    // 32 KiB
  __shared__ unsigned int wsum[16], woff[16];
  __shared__ unsigned int kcnt;
  const int b = blockIdx.x;
  const int tid = threadIdx.x;
  const int lane = tid & 63;
  const int w = tid >> 6;
  const float* __restrict__ pb = pred + (size_t)b * NN * ROWL;
  const int count = (int)cnt[b * CNT_STRIDE];
  if (tid == 0) kcnt = 0u;
  __syncthreads();

  // ---- prefetch: counters + first 64 bucket keys for this wave's 5 classes ----
  unsigned int pcv[5];
  unsigned long long vpre[5];
  #pragma unroll
  for (int cc = 0; cc < 5; ++cc) {
    const int c = w + (cc << 4);
    pcv[cc] = pcnt[(b * NC + c) * PCNT_STRIDE];
    vpre[cc] = buckets[((size_t)(b * NC + c) << 8) + lane];
  }

  // ---- phase E: per-class sort + greedy NMS; kept -> vkeys[0..kcnt) ----
  // Cross-class IoU exactly 0 (cls*7680 offset) -> per-class greedy == ref global scan.
  #pragma unroll 1
  for (int cc = 0; cc < 5; ++cc) {
    const int c = w + (cc << 4);
    int n_c = (int)(pcv[cc] < (unsigned)CCAP ? pcv[cc] : (unsigned)CCAP);
    if (n_c == 0) continue;
    const unsigned long long* __restrict__ bkc = buckets + ((size_t)(b * NC + c) << 8);
    const float offc = (float)c * MAX_WH_F;

    if (n_c <= 64 && count <= KTOP) {
      // ======== fast path (proven R7-R13 code) ========
      unsigned long long v0 = vpre[cc];
      if (lane >= n_c) v0 = 0ull;              // stale slots guarded after count known
      for (int k2 = 2; k2 <= 64; k2 <<= 1) {
        for (int j = k2 >> 1; j >= 1; j >>= 1) {
          unsigned long long vo = __shfl_xor(v0, j, 64);
          bool desc = ((lane & k2) == 0);
          bool low = ((lane & j) == 0);
          if ((desc == low) ? (vo > v0) : (vo < v0)) v0 = vo;
        }
      }
      float x1 = 0.f, y1 = 0.f, x2 = 0.f, y2 = 0.f, aar = 0.f;
      const bool inr = (lane < n_c);
      if (inr) {
        unsigned int lo = (unsigned int)v0;
        int aa = (int)((~(lo >> 16)) & 0xFFFFu);
        const float* row = pb + (size_t)aa * ROWL;
        float cx = row[0], cy = row[1], w2 = row[2], h2 = row[3];
        x1 = (cx - w2 / 2.0f) + offc;
        y1 = (cy - h2 / 2.0f) + offc;
        x2 = (cx + w2 / 2.0f) + offc;
        y2 = (cy + h2 / 2.0f) + offc;
        aar = (x2 - x1) * (y2 - y1);
      }
      // pairwise suppression rows (independent iterations, pipelined)
      unsigned long long rowreg = 0ull;
      for (int i2 = 0; i2 < n_c; ++i2) {
        float bx1 = __shfl(x1, i2, 64), by1 = __shfl(y1, i2, 64);
        float bx2 = __shfl(x2, i2, 64), by2 = __shfl(y2, i2, 64);
        float bar = __shfl(aar, i2, 64);
        bool sup = inr && (lane > i2) &&
                   iou_sup(bx1, by1, bx2, by2, bar, x1, y1, x2, y2, aar);
        unsigned long long rm = __ballot(sup);
        if (lane == i2) rowreg = rm;   // lane i holds "who i suppresses" (j>i bits)
      }
      // greedy resolve, pure bit ops
      unsigned long long cand = (n_c >= 64) ? ~0ull : ((1ull << n_c) - 1ull);
      unsigned long long keepm = 0ull;
      while (cand) {
        int i = __ffsll(cand) - 1;
        keepm |= (1ull << i);
        unsigned long long rowi = __shfl(rowreg, i, 64);
        cand &= ~rowi;
        cand &= ~(1ull << i);
      }
      int keep0 = (int)((keepm >> lane) & 1ull);
      unsigned long long m0 = __ballot(keep0 != 0);
      int tot = (int)__popcll(m0);
      unsigned int base3 = 0;
      if (lane == 0) base3 = atomicAdd(&kcnt, (unsigned int)tot);
      base3 = (unsigned int)__shfl((int)base3, 0, 64);
      if (keep0) {
        unsigned int slot = base3 + (unsigned int)__popcll(m0 & ((1ull << lane) - 1ull));
        if (slot < (unsigned)KTOP) vkeys[slot] = v0;
      }
    } else {
      // ======== slow path (n_c>64 or count>KTOP): proven round-4 code ========
      unsigned long long v[4];
      #pragma unroll
      for (int r = 0; r < 4; ++r) {
        int e = (r << 6) + lane;
        v[r] = (e < n_c) ? bkc[e] : 0ull;
      }
      if (count > KTOP) {
        // dead path statistically: image-wide 4096th-key threshold (bitwise search)
        unsigned long long T = 0ull;
        for (int bit = 63; bit >= 0; --bit) {
          unsigned long long T2 = T | (1ull << bit);
          int cge = 0;
          for (int c2 = 0; c2 < NC; ++c2) {
            unsigned int p2 = pcnt[(b * NC + c2) * PCNT_STRIDE];
            int n2 = (int)(p2 < (unsigned)CCAP ? p2 : (unsigned)CCAP);
            const unsigned long long* bk2 = buckets + ((size_t)(b * NC + c2) << 8);
            for (int base2 = 0; base2 < n2; base2 += 64) {
              int i = base2 + lane;
              bool ge = (i < n2) && (bk2[i] >= T2);
              cge += (int)__popcll(__ballot(ge));
            }
          }
          if (cge >= KTOP) T = T2;   // keys unique -> exactly KTOP keys >= final T
        }
        #pragma unroll
        for (int r = 0; r < 4; ++r) if (v[r] < T) v[r] = 0ull;
        n_c = 0;
        #pragma unroll
        for (int r = 0; r < 4; ++r) n_c += (int)__popcll(__ballot(v[r] != 0ull));
        if (n_c == 0) continue;
      }
      for (int k2 = 2; k2 <= 256; k2 <<= 1) {
        if (k2 == 256) {
          #pragma unroll
          for (int r = 0; r < 2; ++r) {
            unsigned e = (unsigned)((r << 6) + lane);
            bool desc = ((e & k2) == 0);
            unsigned long long lo_ = v[r], hi_ = v[r + 2];
            bool sw = desc ? (lo_ < hi_) : (lo_ > hi_);
            v[r] = sw ? hi_ : lo_; v[r + 2] = sw ? lo_ : hi_;
          }
        }
        if (k2 >= 128) {
          #pragma unroll
          for (int rr = 0; rr < 2; ++rr) {
            int r = rr * 2;
            unsigned e = (unsigned)((r << 6) + lane);
            bool desc = ((e & k2) == 0);
            unsigned long long lo_ = v[r], hi_ = v[r + 1];
            bool sw = desc ? (lo_ < hi_) : (lo_ > hi_);
            v[r] = sw ? hi_ : lo_; v[r + 1] = sw ? lo_ : hi_;
          }
        }
        int j0 = (k2 >> 1) < 32 ? (k2 >> 1) : 32;
        for (int j = j0; j >= 1; j >>= 1) {
          #pragma unroll
          for (int r = 0; r < 4; ++r) {
            unsigned e = (unsigned)((r << 6) + lane);
            unsigned long long vo = __shfl_xor(v[r], j, 64);
            bool desc = ((e & k2) == 0);
            bool low = ((e & j) == 0);
            if ((desc == low) ? (vo > v[r]) : (vo < v[r])) v[r] = vo;
          }
        }
      }
      float x1r[4], y1r[4], x2r[4], y2r[4], ar[4];
      int keepr[4];
      #pragma unroll
      for (int r = 0; r < 4; ++r) {
        int e = (r << 6) + lane;
        keepr[r] = 0; x1r[r] = 0.f; y1r[r] = 0.f; x2r[r] = 0.f; y2r[r] = 0.f; ar[r] = 0.f;
        if (e < n_c) {
          unsigned int lo = (unsigned int)v[r];
          int aa = (int)((~(lo >> 16)) & 0xFFFFu);
          const float* row = pb + (size_t)aa * ROWL;
          float cx = row[0], cy = row[1], w2 = row[2], h2 = row[3];
          x1r[r] = (cx - w2 / 2.0f) + offc;
          y1r[r] = (cy - h2 / 2.0f) + offc;
          x2r[r] = (cx + w2 / 2.0f) + offc;
          y2r[r] = (cy + h2 / 2.0f) + offc;
          ar[r] = (x2r[r] - x1r[r]) * (y2r[r] - y1r[r]);
          keepr[r] = 1;
        }
      }
      for (int i2 = 0; i2 < n_c; ++i2) {
        int ci = i2 >> 6, li = i2 & 63;
        int ki; float bx1v, by1v, bx2v, by2v, bav;
        #define BCAST(R) { ki = __shfl(keepr[R], li, 64); bx1v = __shfl(x1r[R], li, 64); \
                           by1v = __shfl(y1r[R], li, 64); bx2v = __shfl(x2r[R], li, 64); \
                           by2v = __shfl(y2r[R], li, 64); bav = __shfl(ar[R], li, 64); }
        switch (ci) {
          case 0: BCAST(0); break;
          case 1: BCAST(1); break;
          case 2: BCAST(2); break;
          default: BCAST(3); break;
        }
        #undef BCAST
        if (!ki) continue;
        #pragma unroll
        for (int r = 0; r < 4; ++r) {
          int e = (r << 6) + lane;
          if (keepr[r] && e > i2 &&
              iou_sup(bx1v, by1v, bx2v, by2v, bav, x1r[r], y1r[r], x2r[r], y2r[r], ar[r]))
            keepr[r] = 0;
        }
      }
      unsigned long long m[4];
      int tot = 0;
      #pragma unroll
      for (int r = 0; r < 4; ++r) {
        m[r] = __ballot(keepr[r] != 0);
        tot += (int)__popcll(m[r]);
      }
      unsigned int base3 = 0;
      if (lane == 0) base3 = atomicAdd(&kcnt, (unsigned int)tot);
      base3 = (unsigned int)__shfl((int)base3, 0, 64);
      unsigned int start = base3;
      #pragma unroll
      for (int r = 0; r < 4; ++r) {
        if (keepr[r]) {
          unsigned int slot = start + (unsigned int)__popcll(m[r] & ((1ull << lane) - 1ull));
          if (slot < (unsigned)KTOP) vkeys[slot] = v[r];
        }
        start += (unsigned int)__popcll(m[r]);
      }
    }
  }
  __syncthreads();

  // ---- phase F: histogram rank + transform + output (proven R10/R13 finalize) ----
  const int kc = (int)(kcnt < (unsigned)KTOP ? kcnt : (unsigned)KTOP);
  hist[2 * tid] = 0u; hist[2 * tid + 1] = 0u;
  __syncthreads();

  unsigned long long myk[4];
  int myb[4];
  #pragma unroll
  for (int r = 0; r < 4; ++r) {
    int i = tid + (r << 10);
    myb[r] = -1; myk[r] = 0ull;
    if (i < kc) {
      unsigned long long k = vkeys[i];
      int bin = (int)((k >> 44) & (unsigned long long)(NBIN - 1));
      myk[r] = k; myb[r] = bin;
      atomicAdd(&hist[bin], 1u);
    }
  }
  __syncthreads();

  unsigned int h0 = hist[2 * tid], h1 = hist[2 * tid + 1];
  unsigned int v = h0 + h1;
  #pragma unroll
  for (int off = 1; off < 64; off <<= 1) {   // inclusive SUFFIX within wave
    unsigned int o = __shfl_down(v, off, 64);
    if (lane + off < 64) v += o;
  }
  if (lane == 0) wsum[w] = v;
  __syncthreads();
  if (tid < 16) {
    unsigned int s = 0;
    for (int j = tid + 1; j < 16; ++j) s += wsum[j];
    woff[tid] = s;
  }
  __syncthreads();
  unsigned int incl = v + woff[w];
  unsigned int excl = incl - (h0 + h1);
  sufx[2 * tid] = excl + h1;
  sufx[2 * tid + 1] = excl;
  curs[2 * tid] = excl + h1;
  curs[2 * tid + 1] = excl;
  __syncthreads();

  #pragma unroll
  for (int r = 0; r < 4; ++r) {
    if (myb[r] >= 0) {
      unsigned int p = atomicAdd(&curs[myb[r]], 1u);
      skey[p] = myk[r];
    }
  }
  __syncthreads();

  const int h = ihp[0], w3 = iwp[0];
  const double gd = fmin(640.0 / (double)h, 640.0 / (double)w3);
  const float gain = (float)gd;
  const float padx = (float)((640.0 - (double)w3 * gd) * 0.5);
  const float pady = (float)((640.0 - (double)h * gd) * 0.5);
  const float wf = (float)w3, hf = (float)h;
  #pragma unroll
  for (int r = 0; r < 4; ++r) {
    if (myb[r] >= 0) {
      unsigned long long k = myk[r];
      unsigned int gstart = sufx[myb[r]];
      unsigned int gcnt = hist[myb[r]];
      unsigned int rank = gstart;
      for (unsigned int j = 0; j < gcnt; ++j)
        rank += (skey[gstart + j] > k) ? 1u : 0u;   // strict >, excludes self
      if (rank < MAXDET) {
        unsigned int lo = (unsigned int)k;
        int aa = (int)((~(lo >> 16)) & 0xFFFFu);
        int cls = (int)(lo & 0xFFFFu);
        float score = __uint_as_float((unsigned int)(k >> 32));
        const float* row = pb + (size_t)aa * ROWL;
        float cx = row[0], cy = row[1], wd = row[2], ht = row[3];
        float x1 = cx - wd / 2.0f, y1 = cy - ht / 2.0f;
        float x2 = cx + wd / 2.0f, y2 = cy + ht / 2.0f;
        x1 = rintf(fminf(fmaxf((x1 - padx) / gain, 0.0f), wf));
        y1 = rintf(fminf(fmaxf((y1 - pady) / gain, 0.0f), hf));
        x2 = rintf(fminf(fmaxf((x2 - padx) / gain, 0.0f), wf));
        y2 = rintf(fminf(fmaxf((y2 - pady) / gain, 0.0f), hf));
        float* o = out + ((size_t)b * MAXDET + (int)rank) * 6;
        o[0] = x1; o[1] = y1; o[2] = x2; o[3] = y2;
        o[4] = score; o[5] = (float)cls;
      }
    }
  }
  // rows [kc, MAXDET): zero-fill
  for (int i = kc + tid; i < MAXDET; i += 1024) {
    float* o = out + ((size_t)b * MAXDET + i) * 6;
    o[0] = 0.0f; o[1] = 0.0f; o[2] = 0.0f; o[3] = 0.0f; o[4] = 0.0f; o[5] = 0.0f;
  }
}

extern "C" void kernel_launch(void* const* d_in, const int* in_sizes, int n_in,
                              void* d_out, int out_size, void* d_ws, size_t ws_size,
                              hipStream_t stream) {
  const float* pred = (const float*)d_in[0];
  const int* ih = (const int*)d_in[1];
  const int* iw = (const int*)d_in[2];
  float* out = (float*)d_out;
  char* ws = (char*)d_ws;

  unsigned int* pcnt = (unsigned int*)ws;
  unsigned int* cnt = (unsigned int*)(ws + OFF_CNT);
  unsigned long long* buckets = (unsigned long long*)(ws + OFF_BUCK);

  zero_kernel<<<ZERO_WORDS / 256, 256, 0, stream>>>((unsigned int*)ws);
  dim3 sgrid((NN + 255) / 256, BB);
  score_kernel<<<sgrid, 256, 0, stream>>>(pred, buckets, pcnt, cnt);
  nms_finalize_kernel<<<BB, 1024, 0, stream>>>(pred, buckets, pcnt, cnt, ih, iw, out);
}

// Round 16
// 71.089 us; speedup vs baseline: 2.3272x; 2.2422x over previous
//
#include <hip/hip_runtime.h>

#define BB 16
#define NN 25200
#define NC 80
#define ROWL 85
#define KTOP 4096
#define MAXDET 1000
#define CONF_T 0.55f
#define IOU_T 0.45f
#define MAX_WH_F 7680.0f
#define CNT_STRIDE 32    // per-image counters 128 B apart
#define PCNT_STRIDE 16   // per-(image,class) counters 64 B apart
#define CCAP 256         // per-class candidate cap (mean ~44, sd ~6.6 -> 30+ sigma)
#define NBIN 2048        // rank histogram bins = key bits [54:44]
#define FBLK 8           // finalize blocks per image

// ws layout (bytes) — R10 layout:
//   pcnt   : [0,      81920)   16*80*16 u32  per-(b,c) bucket counters
//   cnt    : [81920,  83968)   16*32 u32     per-image candidate count
//   kcnt   : [83968,  86016)   16*32 u32     per-image kept count
//   buckets: [86016,  2707456) 16*80*256 u64 per-(b,c) candidate keys
//   kept   : [2707456,3231744) 16*4096 u64   per-image kept pool
#define OFF_CNT   81920
#define OFF_KCNT  83968
#define OFF_BUCK  86016
#define OFF_KEPT  2707456
#define ZERO_WORDS 21504

__global__ void zero_kernel(unsigned int* __restrict__ w) {
  w[blockIdx.x * 256 + threadIdx.x] = 0u;
}

// ---------------- Kernel A: score, 16-lane-group cooperative class scan (R10 verbatim) ----------------
__global__ __launch_bounds__(256) void score_kernel(const float* __restrict__ pred,
                             unsigned long long* __restrict__ buckets,
                             unsigned int* __restrict__ pcnt,
                             unsigned int* __restrict__ cnt) {
  const int b = blockIdx.y;
  const int lane = threadIdx.x & 63;
  const int a0 = blockIdx.x * 256 + (threadIdx.x & ~63);
  const int a = a0 + lane;
  const int g = lane >> 4;     // 16-lane group id [0,4)
  const int gl = lane & 15;    // lane within group
  const float* __restrict__ pb = pred + (size_t)b * NN * ROWL;
  float obj = 0.0f;
  if (a < NN) obj = pb[(size_t)a * ROWL + 4];
  unsigned long long mask = __ballot(obj > CONF_T);
  unsigned int nvacc = 0;
  while (mask) {
    int s0 = __ffsll(mask) - 1; mask &= mask - 1;
    int s1 = -1, s2 = -1, s3 = -1;
    if (mask) { s1 = __ffsll(mask) - 1; mask &= mask - 1; }
    if (mask) { s2 = __ffsll(mask) - 1; mask &= mask - 1; }
    if (mask) { s3 = __ffsll(mask) - 1; mask &= mask - 1; }
    const int sg = (g == 0) ? s0 : (g == 1) ? s1 : (g == 2) ? s2 : s3;
    const bool act = (sg >= 0);
    const int srow = act ? sg : s0;       // inactive groups alias row s0 (broadcast)
    const int aa = a0 + srow;
    const float objg = __shfl(obj, srow, 64);
    const float* __restrict__ row = pb + (size_t)aa * ROWL;
    float best = -1.0f; int bi = gl;
    #pragma unroll
    for (int t = 0; t < 5; ++t) {
      float v = row[5 + gl + 16 * t] * objg;      // exact ref product order
      if (v > best) { best = v; bi = gl + 16 * t; }  // strict > keeps first
    }
    #pragma unroll
    for (int off = 1; off <= 8; off <<= 1) {      // group argmax: value, tie -> min idx
      float ov = __shfl_xor(best, off, 64);
      int oi = __shfl_xor(bi, off, 64);
      if (ov > best || (ov == best && oi < bi)) { best = ov; bi = oi; }
    }
    bool emit = act && (gl == 0) && (best > CONF_T);
    if (emit) {
      // key: score bits | ~anchor (lower anchor first = lax.top_k tie order) | cls
      unsigned long long key =
          ((unsigned long long)__float_as_uint(best) << 32) |
          ((unsigned long long)((~(unsigned)aa) & 0xFFFFu) << 16) |
          (unsigned long long)(unsigned)bi;
      unsigned int slot = atomicAdd(&pcnt[(b * NC + bi) * PCNT_STRIDE], 1u);
      if (slot < CCAP)
        buckets[((size_t)(b * NC + bi) << 8) + slot] = key;
    }
    unsigned long long em = __ballot(emit);
    if (lane == 0) nvacc += (unsigned int)__popcll(em);
  }
  if (lane == 0 && nvacc)
    atomicAdd(&cnt[b * CNT_STRIDE], nvacc);
}

// IoU suppress helper (exact reference arithmetic)
__device__ __forceinline__ bool iou_sup(float ax1, float ay1, float ax2, float ay2,
                                        float aar, float bx1, float by1, float bx2,
                                        float by2, float bar) {
  float ltx = fmaxf(ax1, bx1), lty = fmaxf(ay1, by1);
  float rbx = fminf(ax2, bx2), rby = fminf(ay2, by2);
  float wv = rbx - ltx; wv = wv > 0.0f ? wv : 0.0f;
  float hv = rby - lty; hv = hv > 0.0f ? hv : 0.0f;
  float inter = wv * hv;
  float iou = inter / (aar + bar - inter + 1e-7f);
  return iou > IOU_T;
}

// ---------------- Kernel B: per-(image,class) sort + NMS (R10 verbatim, 1280 blocks) ----------------
// shfl-dense (ds_bpermute on the per-CU LDS pipe): MUST stay spread wide —
// R14 proved 16-block packing serializes ~80 classes on one CU's LDS pipe.
__global__ __launch_bounds__(64) void class_nms_kernel(
    const float* __restrict__ pred,
    const unsigned long long* __restrict__ buckets,
    const unsigned int* __restrict__ pcnt,
    const unsigned int* __restrict__ cnt,
    unsigned long long* __restrict__ kept,
    unsigned int* __restrict__ kcnt) {
  const int c = blockIdx.x;
  const int b = blockIdx.y;
  const int lane = threadIdx.x;
  unsigned int pc = pcnt[(b * NC + c) * PCNT_STRIDE];
  int n_c = (int)(pc < (unsigned)CCAP ? pc : (unsigned)CCAP);
  const unsigned long long* __restrict__ bk = buckets + ((size_t)(b * NC + c) << 8);
  const float* __restrict__ pb = pred + (size_t)b * NN * ROWL;
  const float offc = (float)c * MAX_WH_F;
  const int count = (int)cnt[b * CNT_STRIDE];

  if (n_c == 0) return;

  if (n_c <= 64 && count <= KTOP) {
    // ======== fast path ========
    unsigned long long v0 = (lane < n_c) ? bk[lane] : 0ull;
    for (int k2 = 2; k2 <= 64; k2 <<= 1) {
      for (int j = k2 >> 1; j >= 1; j >>= 1) {
        unsigned long long vo = __shfl_xor(v0, j, 64);
        bool desc = ((lane & k2) == 0);
        bool low = ((lane & j) == 0);
        if ((desc == low) ? (vo > v0) : (vo < v0)) v0 = vo;
      }
    }
    float x1 = 0.f, y1 = 0.f, x2 = 0.f, y2 = 0.f, aar = 0.f;
    const bool inr = (lane < n_c);
    if (inr) {
      unsigned int lo = (unsigned int)v0;
      int aa = (int)((~(lo >> 16)) & 0xFFFFu);
      const float* row = pb + (size_t)aa * ROWL;
      float cx = row[0], cy = row[1], w2 = row[2], h2 = row[3];
      x1 = (cx - w2 / 2.0f) + offc;
      y1 = (cy - h2 / 2.0f) + offc;
      x2 = (cx + w2 / 2.0f) + offc;
      y2 = (cy + h2 / 2.0f) + offc;
      aar = (x2 - x1) * (y2 - y1);
    }
    // phase 1: pairwise suppression rows (independent iterations, pipelined)
    unsigned long long rowreg = 0ull;
    for (int i2 = 0; i2 < n_c; ++i2) {
      float bx1 = __shfl(x1, i2, 64), by1 = __shfl(y1, i2, 64);
      float bx2 = __shfl(x2, i2, 64), by2 = __shfl(y2, i2, 64);
      float bar = __shfl(aar, i2, 64);
      bool sup = inr && (lane > i2) &&
                 iou_sup(bx1, by1, bx2, by2, bar, x1, y1, x2, y2, aar);
      unsigned long long rm = __ballot(sup);
      if (lane == i2) rowreg = rm;   // lane i holds "who i suppresses" (j>i bits)
    }
    // phase 2: greedy resolve, pure bit ops
    unsigned long long cand = (n_c >= 64) ? ~0ull : ((1ull << n_c) - 1ull);
    unsigned long long keepm = 0ull;
    while (cand) {
      int i = __ffsll(cand) - 1;
      keepm |= (1ull << i);
      unsigned long long rowi = __shfl(rowreg, i, 64);
      cand &= ~rowi;
      cand &= ~(1ull << i);
    }
    int keep0 = (int)((keepm >> lane) & 1ull);
    unsigned long long m0 = __ballot(keep0 != 0);
    int tot = (int)__popcll(m0);
    unsigned int base3 = 0;
    if (lane == 0) base3 = atomicAdd(&kcnt[b * CNT_STRIDE], (unsigned int)tot);
    base3 = (unsigned int)__shfl((int)base3, 0, 64);
    if (keep0) {
      unsigned int slot = base3 + (unsigned int)__popcll(m0 & ((1ull << lane) - 1ull));
      if (slot < (unsigned)KTOP) kept[(size_t)b * KTOP + slot] = v0;
    }
    return;
  }

  // ======== slow path (n_c>64 or count>KTOP): proven round-4 code ========
  unsigned long long v[4];
  #pragma unroll
  for (int r = 0; r < 4; ++r) {
    int e = (r << 6) + lane;
    v[r] = (e < n_c) ? bk[e] : 0ull;
  }
  if (count > KTOP) {
    unsigned long long T = 0ull;
    for (int bit = 63; bit >= 0; --bit) {
      unsigned long long T2 = T | (1ull << bit);
      int cge = 0;
      for (int c2 = 0; c2 < NC; ++c2) {
        unsigned int p2 = pcnt[(b * NC + c2) * PCNT_STRIDE];
        int n2 = (int)(p2 < (unsigned)CCAP ? p2 : (unsigned)CCAP);
        const unsigned long long* bk2 = buckets + ((size_t)(b * NC + c2) << 8);
        for (int base2 = 0; base2 < n2; base2 += 64) {
          int i = base2 + lane;
          bool ge = (i < n2) && (bk2[i] >= T2);
          cge += (int)__popcll(__ballot(ge));
        }
      }
      if (cge >= KTOP) T = T2;
    }
    #pragma unroll
    for (int r = 0; r < 4; ++r) if (v[r] < T) v[r] = 0ull;
    n_c = 0;
    #pragma unroll
    for (int r = 0; r < 4; ++r) n_c += (int)__popcll(__ballot(v[r] != 0ull));
    if (n_c == 0) return;
  }
  for (int k2 = 2; k2 <= 256; k2 <<= 1) {
    if (k2 == 256) {
      #pragma unroll
      for (int r = 0; r < 2; ++r) {
        unsigned e = (unsigned)((r << 6) + lane);
        bool desc = ((e & k2) == 0);
        unsigned long long lo_ = v[r], hi_ = v[r + 2];
        bool sw = desc ? (lo_ < hi_) : (lo_ > hi_);
        v[r] = sw ? hi_ : lo_; v[r + 2] = sw ? lo_ : hi_;
      }
    }
    if (k2 >= 128) {
      #pragma unroll
      for (int rr = 0; rr < 2; ++rr) {
        int r = rr * 2;
        unsigned e = (unsigned)((r << 6) + lane);
        bool desc = ((e & k2) == 0);
        unsigned long long lo_ = v[r], hi_ = v[r + 1];
        bool sw = desc ? (lo_ < hi_) : (lo_ > hi_);
        v[r] = sw ? hi_ : lo_; v[r + 1] = sw ? lo_ : hi_;
      }
    }
    int j0 = (k2 >> 1) < 32 ? (k2 >> 1) : 32;
    for (int j = j0; j >= 1; j >>= 1) {
      #pragma unroll
      for (int r = 0; r < 4; ++r) {
        unsigned e = (unsigned)((r << 6) + lane);
        unsigned long long vo = __shfl_xor(v[r], j, 64);
        bool desc = ((e & k2) == 0);
        bool low = ((e & j) == 0);
        if ((desc == low) ? (vo > v[r]) : (vo < v[r])) v[r] = vo;
      }
    }
  }
  float x1r[4], y1r[4], x2r[4], y2r[4], ar[4];
  int keepr[4];
  #pragma unroll
  for (int r = 0; r < 4; ++r) {
    int e = (r << 6) + lane;
    keepr[r] = 0; x1r[r] = 0.f; y1r[r] = 0.f; x2r[r] = 0.f; y2r[r] = 0.f; ar[r] = 0.f;
    if (e < n_c) {
      unsigned int lo = (unsigned int)v[r];
      int aa = (int)((~(lo >> 16)) & 0xFFFFu);
      const float* row = pb + (size_t)aa * ROWL;
      float cx = row[0], cy = row[1], w2 = row[2], h2 = row[3];
      x1r[r] = (cx - w2 / 2.0f) + offc;
      y1r[r] = (cy - h2 / 2.0f) + offc;
      x2r[r] = (cx + w2 / 2.0f) + offc;
      y2r[r] = (cy + h2 / 2.0f) + offc;
      ar[r] = (x2r[r] - x1r[r]) * (y2r[r] - y1r[r]);
      keepr[r] = 1;
    }
  }
  for (int i2 = 0; i2 < n_c; ++i2) {
    int ci = i2 >> 6, li = i2 & 63;
    int ki; float bx1v, by1v, bx2v, by2v, bav;
    #define BCAST(R) { ki = __shfl(keepr[R], li, 64); bx1v = __shfl(x1r[R], li, 64); \
                       by1v = __shfl(y1r[R], li, 64); bx2v = __shfl(x2r[R], li, 64); \
                       by2v = __shfl(y2r[R], li, 64); bav = __shfl(ar[R], li, 64); }
    switch (ci) {
      case 0: BCAST(0); break;
      case 1: BCAST(1); break;
      case 2: BCAST(2); break;
      default: BCAST(3); break;
    }
    #undef BCAST
    if (!ki) continue;
    #pragma unroll
    for (int r = 0; r < 4; ++r) {
      int e = (r << 6) + lane;
      if (keepr[r] && e > i2 &&
          iou_sup(bx1v, by1v, bx2v, by2v, bav, x1r[r], y1r[r], x2r[r], y2r[r], ar[r]))
        keepr[r] = 0;
    }
  }
  unsigned long long m[4];
  int tot = 0;
  #pragma unroll
  for (int r = 0; r < 4; ++r) {
    m[r] = __ballot(keepr[r] != 0);
    tot += (int)__popcll(m[r]);
  }
  unsigned int base3 = 0;
  if (lane == 0) base3 = atomicAdd(&kcnt[b * CNT_STRIDE], (unsigned int)tot);
  base3 = (unsigned int)__shfl((int)base3, 0, 64);
  unsigned int start = base3;
  #pragma unroll
  for (int r = 0; r < 4; ++r) {
    if (keepr[r]) {
      unsigned int slot = start + (unsigned int)__popcll(m[r] & ((1ull << lane) - 1ull));
      if (slot < (unsigned)KTOP) kept[(size_t)b * KTOP + slot] = v[r];
    }
    start += (unsigned int)__popcll(m[r]);
  }
}

// ---------------- Kernel C: histogram rank + transform + write, FBLK blocks/image ----------------
// Each of the FBLK blocks per image redundantly builds the full histogram +
// suffix scan + bin scatter (3-4 coalesced rounds; ranks come from key VALUES,
// so per-block scatter order is irrelevant), then ranks/transforms/writes ONLY
// its 1/FBLK slice — spreading the latency-bound scattered pred gather across
// 8x more CUs (R10's 16-block finalize ran this at 2.4% occupancy, ~30us).
__global__ __launch_bounds__(1024) void finalize_kernel(
    const float* __restrict__ pred,
    const unsigned long long* __restrict__ kept,
    const unsigned int* __restrict__ kcnt,
    const int* __restrict__ ihp, const int* __restrict__ iwp,
    float* __restrict__ out) {
  __shared__ unsigned int hist[NBIN];        // 8 KiB
  __shared__ unsigned int sufx[NBIN];        // 8 KiB
  __shared__ unsigned int curs[NBIN];        // 8 KiB
  __shared__ unsigned int wsum[16], woff[16];
  __shared__ unsigned long long skey[KTOP];  // 32 KiB
  const int q = blockIdx.x;                  // slice id [0, FBLK)
  const int b = blockIdx.y;
  const int tid = threadIdx.x;
  const int lane = tid & 63;
  const int w = tid >> 6;
  unsigned int kcr = kcnt[b * CNT_STRIDE];
  const int kc = (int)(kcr < (unsigned)KTOP ? kcr : (unsigned)KTOP);
  const unsigned long long* __restrict__ kb = kept + (size_t)b * KTOP;

  hist[2 * tid] = 0u; hist[2 * tid + 1] = 0u;
  __syncthreads();

  // P1: full histogram over all kc keys (coalesced rounds)
  for (int i = tid; i < kc; i += 1024) {
    unsigned long long k = kb[i];
    atomicAdd(&hist[(int)((k >> 44) & (unsigned long long)(NBIN - 1))], 1u);
  }
  __syncthreads();

  // P2: suffix-exclusive sums (descending), wave-level scan (R10 verbatim)
  unsigned int h0 = hist[2 * tid], h1 = hist[2 * tid + 1];
  unsigned int v = h0 + h1;
  #pragma unroll
  for (int off = 1; off < 64; off <<= 1) {   // inclusive SUFFIX within wave
    unsigned int o = __shfl_down(v, off, 64);
    if (lane + off < 64) v += o;
  }
  if (lane == 0) wsum[w] = v;
  __syncthreads();
  if (tid < 16) {
    unsigned int s = 0;
    for (int j = tid + 1; j < 16; ++j) s += wsum[j];
    woff[tid] = s;
  }
  __syncthreads();
  unsigned int incl = v + woff[w];
  unsigned int excl = incl - (h0 + h1);
  sufx[2 * tid] = excl + h1;
  sufx[2 * tid + 1] = excl;
  curs[2 * tid] = excl + h1;
  curs[2 * tid + 1] = excl;
  __syncthreads();

  // P3: scatter ALL keys grouped by bin (order within bin arbitrary)
  for (int i = tid; i < kc; i += 1024) {
    unsigned long long k = kb[i];
    unsigned int p = atomicAdd(&curs[(int)((k >> 44) & (unsigned long long)(NBIN - 1))], 1u);
    skey[p] = k;
  }
  __syncthreads();

  // P4: rank + transform + write MY slice [q*qlen, min((q+1)*qlen, kc))
  const int h = ihp[0], w3 = iwp[0];
  const double gd = fmin(640.0 / (double)h, 640.0 / (double)w3);
  const float gain = (float)gd;
  const float padx = (float)((640.0 - (double)w3 * gd) * 0.5);
  const float pady = (float)((640.0 - (double)h * gd) * 0.5);
  const float wf = (float)w3, hf = (float)h;
  const int qlen = (kc + FBLK - 1) / FBLK;   // <= 512 (kc <= 4096)
  const int i = q * qlen + tid;
  if (tid < qlen && i < kc) {
    unsigned long long k = kb[i];
    int bin = (int)((k >> 44) & (unsigned long long)(NBIN - 1));
    unsigned int gstart = sufx[bin];
    unsigned int gcnt = hist[bin];
    unsigned int rank = gstart;
    for (unsigned int j = 0; j < gcnt; ++j)
      rank += (skey[gstart + j] > k) ? 1u : 0u;   // strict >, excludes self
    if (rank < MAXDET) {
      unsigned int lo = (unsigned int)k;
      int aa = (int)((~(lo >> 16)) & 0xFFFFu);
      int cls = (int)(lo & 0xFFFFu);
      float score = __uint_as_float((unsigned int)(k >> 32));
      const float* row = pred + ((size_t)b * NN + aa) * ROWL;
      float cx = row[0], cy = row[1], wd = row[2], ht = row[3];
      float x1 = cx - wd / 2.0f, y1 = cy - ht / 2.0f;
      float x2 = cx + wd / 2.0f, y2 = cy + ht / 2.0f;
      x1 = rintf(fminf(fmaxf((x1 - padx) / gain, 0.0f), wf));
      y1 = rintf(fminf(fmaxf((y1 - pady) / gain, 0.0f), hf));
      x2 = rintf(fminf(fmaxf((x2 - padx) / gain, 0.0f), wf));
      y2 = rintf(fminf(fmaxf((y2 - pady) / gain, 0.0f), hf));
      float* o = out + ((size_t)b * MAXDET + (int)rank) * 6;
      o[0] = x1; o[1] = y1; o[2] = x2; o[3] = y2;
      o[4] = score; o[5] = (float)cls;
    }
  }
  // rows [kc, MAXDET): zero-fill, disjoint across the FBLK blocks
  {
    int i2 = kc + q * 1024 + tid;   // FBLK*1024 = 8192 >= MAXDET - kc always
    if (i2 < MAXDET) {
      float* o = out + ((size_t)b * MAXDET + i2) * 6;
      o[0] = 0.0f; o[1] = 0.0f; o[2] = 0.0f; o[3] = 0.0f; o[4] = 0.0f; o[5] = 0.0f;
    }
  }
}

extern "C" void kernel_launch(void* const* d_in, const int* in_sizes, int n_in,
                              void* d_out, int out_size, void* d_ws, size_t ws_size,
                              hipStream_t stream) {
  const float* pred = (const float*)d_in[0];
  const int* ih = (const int*)d_in[1];
  const int* iw = (const int*)d_in[2];
  float* out = (float*)d_out;
  char* ws = (char*)d_ws;

  unsigned int* pcnt = (unsigned int*)ws;
  unsigned int* cnt = (unsigned int*)(ws + OFF_CNT);
  unsigned int* kcnt = (unsigned int*)(ws + OFF_KCNT);
  unsigned long long* buckets = (unsigned long long*)(ws + OFF_BUCK);
  unsigned long long* kept = (unsigned long long*)(ws + OFF_KEPT);

  zero_kernel<<<ZERO_WORDS / 256, 256, 0, stream>>>((unsigned int*)ws);
  dim3 sgrid((NN + 255) / 256, BB);
  score_kernel<<<sgrid, 256, 0, stream>>>(pred, buckets, pcnt, cnt);
  dim3 cgrid(NC, BB);
  class_nms_kernel<<<cgrid, 64, 0, stream>>>(pred, buckets, pcnt, cnt, kept, kcnt);
  dim3 fgrid(FBLK, BB);
  finalize_kernel<<<fgrid, 1024, 0, stream>>>(pred, kept, kcnt, ih, iw, out);
}